// Round 1
// baseline (5126.726 us; speedup 1.0000x reference)
//
#include <hip/hip_runtime.h>
#include <cstdint>
#include <climits>

#define N 8192
#define D 64
#define H 128
#define O 64
#define KNB 16
#define NE (N*KNB)        // 131072
#define ETOT (NE + N)     // 139264
#define OUT0 (N*D)        // 524288

__device__ __forceinline__ float bf2f(unsigned short u){
    union { unsigned int u; float f; } v; v.u = ((unsigned int)u) << 16; return v.f;
}
__device__ __forceinline__ unsigned short f2bf(float f){
    union { float f; unsigned int u; } v; v.f = f;
    unsigned int r = v.u + 0x7FFFu + ((v.u >> 16) & 1u);   // RNE
    return (unsigned short)(r >> 16);
}

// ---------------- dtype probe: 1=bf16 inputs, 0=fp32 inputs ----------------
__global__ void k_probe(const unsigned short* __restrict__ x, int* __restrict__ flag){
    __shared__ int cnt;
    if (threadIdx.x == 0) cnt = 0;
    __syncthreads();
    unsigned short u = x[2*threadIdx.x];
    int e = (u >> 7) & 0xFF;
    int ok = (u == 0) || (e >= 0x60 && e <= 0x85);
    unsigned long long m = __ballot(ok);
    if ((threadIdx.x & 63) == 0) atomicAdd(&cnt, __popcll(m));
    __syncthreads();
    if (threadIdx.x == 0) *flag = (cnt >= 128) ? 1 : 0;
}

// ---------------- generic input convert -> fp32 ----------------
__global__ void k_cvt(const void* __restrict__ src, float* __restrict__ dst,
                      int n, const int* __restrict__ flag){
    int i = blockIdx.x*256 + threadIdx.x;
    if (i >= n) return;
    if (*flag) dst[i] = bf2f(((const unsigned short*)src)[i]);
    else       dst[i] = ((const float*)src)[i];
}

// ---------------- row norms: EXACT numpy fp32 pairwise semantics ----------------
__global__ void k_prep(const float* __restrict__ xf, float* __restrict__ nrmf){
    int i = blockIdx.x*64 + threadIdx.x;
    const float* xr = xf + i*D;
    float r[8];
    #pragma unroll
    for (int q = 0; q < 8; ++q) r[q] = __fmul_rn(xr[q], xr[q]);
    #pragma unroll
    for (int b = 8; b < 64; b += 8)
        #pragma unroll
        for (int q = 0; q < 8; ++q)
            r[q] = __fadd_rn(r[q], __fmul_rn(xr[b+q], xr[b+q]));
    float s = __fadd_rn(__fadd_rn(__fadd_rn(r[0],r[1]), __fadd_rn(r[2],r[3])),
                        __fadd_rn(__fadd_rn(r[4],r[5]), __fadd_rn(r[6],r[7])));
    nrmf[i] = __fsqrt_rn(s);
}

// ---------------- topk: 32 queries/block, j-range split in 2 ----------------
// Grid: 512 blocks of 512 threads. Block (grp, split): queries i = grp*32+q
// (q = tid&31), scans j in [split*4096, (split+1)*4096). Thread (q, m=tid>>5)
// runs two interleaved fp32 FMA chains (j0 = m+32s, j1 = j0+16).
// Sim semantics bitwise-identical to the previous passing kernel:
//   sequential fp32 FMA k=0..63, den = fadd(fmul(ni,nj),1e-8), s = fdiv(a,den).
// The divide is deferred behind a provably-conservative prefilter
// (a > thr - |thr|*1e-6, thr = lv[15]*den); an EXACT recheck (s > lv[15])
// gates the insertion, so list evolution is identical.
// Per-query merge of the 16 per-thread sorted lists is a k-way cursor merge:
// heads published to padded LDS (stride 17 -> conflict-free), winner shifts
// its register list (statically unrolled). Partial (raw-value) top-16 per
// split goes to global; k_merge fuses the two splits exactly.
__global__ __launch_bounds__(512, 4) void k_topk(const float* __restrict__ xf,
                                                 const float* __restrict__ nrmf,
                                                 float* __restrict__ partVal,
                                                 int* __restrict__ partIdx){
    __shared__ float cv[544];   // [q*17 + m] head values (stride 17: bank-clean)
    __shared__ int   ci[544];   // head indices
    __shared__ int   wm[32];    // winning m per query per round

    int tid = threadIdx.x;
    int q = tid & 31, m = tid >> 5;
    int grp = blockIdx.x >> 1;
    int split = blockIdx.x & 1;
    int i = grp*32 + q;
    int jbase = split*4096;

    const float4* xip = (const float4*)(xf + (size_t)i*D);
    float4 xi4[16];
    #pragma unroll
    for (int c = 0; c < 16; ++c) xi4[c] = xip[c];
    float ni = nrmf[i];

    float lv[16]; int li[16];
    #pragma unroll
    for (int r = 0; r < 16; ++r){ lv[r] = -3.0e38f; li[r] = INT_MAX; }

    for (int s = 0; s < 128; ++s){
        int j0 = jbase + m + 32*s;
        int j1 = j0 + 16;
        const float4* A0 = (const float4*)(xf + (size_t)j0*D);
        const float4* A1 = (const float4*)(xf + (size_t)j1*D);
        float a0 = 0.0f, a1 = 0.0f;
        #pragma unroll
        for (int c = 0; c < 16; ++c){
            float4 b0 = A0[c], b1 = A1[c], xa = xi4[c];
            a0 = __fmaf_rn(b0.x, xa.x, a0);
            a0 = __fmaf_rn(b0.y, xa.y, a0);
            a0 = __fmaf_rn(b0.z, xa.z, a0);
            a0 = __fmaf_rn(b0.w, xa.w, a0);
            a1 = __fmaf_rn(b1.x, xa.x, a1);
            a1 = __fmaf_rn(b1.y, xa.y, a1);
            a1 = __fmaf_rn(b1.z, xa.z, a1);
            a1 = __fmaf_rn(b1.w, xa.w, a1);
        }
        float den0 = __fadd_rn(__fmul_rn(ni, nrmf[j0]), 1e-8f);
        float den1 = __fadd_rn(__fmul_rn(ni, nrmf[j1]), 1e-8f);
        // chain 0: conservative prefilter, exact recheck
        float thr0 = lv[15]*den0;
        if (j0 != i && a0 > __fmaf_rn(fabsf(thr0), -1e-6f, thr0)){
            float s0 = __fdiv_rn(a0, den0);
            if (s0 > lv[15]){
                lv[15] = s0; li[15] = j0;
                #pragma unroll
                for (int r = 15; r > 0; --r){
                    if (lv[r] > lv[r-1]){
                        float tv = lv[r]; lv[r] = lv[r-1]; lv[r-1] = tv;
                        int ti = li[r]; li[r] = li[r-1]; li[r-1] = ti;
                    }
                }
            }
        }
        // chain 1 (sees post-chain0 list state, same as before)
        float thr1 = lv[15]*den1;
        if (j1 != i && a1 > __fmaf_rn(fabsf(thr1), -1e-6f, thr1)){
            float s1 = __fdiv_rn(a1, den1);
            if (s1 > lv[15]){
                lv[15] = s1; li[15] = j1;
                #pragma unroll
                for (int r = 15; r > 0; --r){
                    if (lv[r] > lv[r-1]){
                        float tv = lv[r]; lv[r] = lv[r-1]; lv[r-1] = tv;
                        int ti = li[r]; li[r] = li[r-1]; li[r-1] = ti;
                    }
                }
            }
        }
    }

    // publish heads
    cv[q*17 + m] = lv[0];
    ci[q*17 + m] = li[0];
    __syncthreads();

    for (int sel = 0; sel < KNB; ++sel){
        if (tid < 32){
            int q2 = tid;
            float fv = -3.0e38f; int fi = INT_MAX; int fm = 0;
            #pragma unroll
            for (int c = 0; c < 16; ++c){
                float v = cv[q2*17 + c]; int id = ci[q2*17 + c];
                if (v > fv || (v == fv && id < fi)){ fv = v; fi = id; fm = c; }
            }
            int i2 = grp*32 + q2;
            int base = (split*N + i2)*KNB + sel;
            partVal[base] = fv;      // RAW value; threshold applied in k_merge
            partIdx[base] = fi;
            wm[q2] = fm;
        }
        __syncthreads();
        if (sel < KNB-1 && m == wm[q]){
            #pragma unroll
            for (int r = 0; r < 15; ++r){ lv[r] = lv[r+1]; li[r] = li[r+1]; }
            lv[15] = -3.0e38f; li[15] = INT_MAX;
            cv[q*17 + m] = lv[0];
            ci[q*17 + m] = li[0];
        }
        __syncthreads();
    }
}

// ---------------- merge the 2 j-split partial lists per query ----------------
__global__ void k_merge(const float* __restrict__ pV, const int* __restrict__ pI,
                        int* __restrict__ topIdx, float* __restrict__ ewArr){
    int qq = blockIdx.x*256 + threadIdx.x;
    const float* A  = pV + (size_t)qq*KNB;
    const float* B  = pV + (size_t)(N + qq)*KNB;
    const int*   AI = pI + (size_t)qq*KNB;
    const int*   BI = pI + (size_t)(N + qq)*KNB;
    int ai = 0, bi = 0;
    #pragma unroll
    for (int sel = 0; sel < KNB; ++sel){
        float va = A[ai], vb = B[bi];
        int ia = AI[ai], ib = BI[bi];
        bool tA = (va > vb) || (va == vb && ia < ib);
        float v = tA ? va : vb;
        int  id = tA ? ia : ib;
        ai += tA ? 1 : 0; bi += tA ? 0 : 1;
        topIdx[qq*KNB + sel] = id;
        ewArr [qq*KNB + sel] = (v > 0.5f) ? v : 0.0f;
    }
}

// ---------------- degree / dinv ----------------
__global__ void k_deg_init(double* __restrict__ degD){
    int j = blockIdx.x*blockDim.x + threadIdx.x;
    if (j < N) degD[j] = 2.0;
}
__global__ void k_deg_scatter(const int* __restrict__ topIdx, const float* __restrict__ ewArr,
                              double* __restrict__ degD){
    int e = blockIdx.x*blockDim.x + threadIdx.x;
    if (e < NE){
        float w = ewArr[e];
        if (w > 0.0f) atomicAdd(&degD[topIdx[e]], (double)w);
    }
}
__global__ void k_dinv(const double* __restrict__ degD, float* __restrict__ dinv){
    int j = blockIdx.x*blockDim.x + threadIdx.x;
    if (j < N) dinv[j] = (float)(1.0 / sqrt(degD[j]));
}

// ---------------- dense matmuls ----------------
__global__ void k_gemm1(const float* __restrict__ xf, const float* __restrict__ W1,
                        float* __restrict__ h1){
    int id = blockIdx.x*256 + threadIdx.x;
    int i = id >> 7; int f = id & (H-1);
    const float* xr = xf + i*D;
    float acc = 0.f;
    #pragma unroll
    for (int k = 0; k < D; ++k) acc += xr[k] * W1[k*H + f];
    h1[id] = acc;
}
__global__ void k_gemm2(const float* __restrict__ z1, const float* __restrict__ W2,
                        float* __restrict__ h2){
    int id = blockIdx.x*256 + threadIdx.x;
    int i = id >> 6; int f = id & (O-1);
    const float* zr = z1 + i*H;
    float acc = 0.f;
    #pragma unroll
    for (int k = 0; k < H; ++k) acc += zr[k] * W2[k*O + f];
    h2[id] = acc;
}
__global__ void k_proj(const float* __restrict__ z2, const float* __restrict__ Wp,
                       const float* __restrict__ bp, float* __restrict__ z3){
    int id = blockIdx.x*256 + threadIdx.x;
    int i = id >> 6; int f = id & (D-1);
    const float* zr = z2 + i*O;
    float acc = bp[f];
    #pragma unroll
    for (int k = 0; k < O; ++k) acc += zr[k] * Wp[k*D + f];
    z3[id] = acc;
}

// ---------------- GCN aggregation ----------------
template<int F>
__global__ void k_agg_init(const float* __restrict__ h, const float* __restrict__ dinv,
                           float* __restrict__ agg){
    int id = blockIdx.x*256 + threadIdx.x;
    int j = id / F;
    float dj = dinv[j];
    agg[id] = 2.f * dj * dj * h[id];
}
template<int F>
__global__ void k_agg_scat(const int* __restrict__ topIdx, const float* __restrict__ ewArr,
                           const float* __restrict__ dinv, const float* __restrict__ h,
                           float* __restrict__ agg){
    int e = blockIdx.x; int f = threadIdx.x;
    float w = ewArr[e];
    if (w == 0.f) return;
    int s = e >> 4;
    int dn = topIdx[e];
    float c = dinv[s] * w * dinv[dn];
    atomicAdd(&agg[dn*F + f], c * h[s*F + f]);
}

// ---------------- bias + relu + layernorm ----------------
__global__ void k_post128(const float* __restrict__ agg, const float* __restrict__ b,
                          const float* __restrict__ g, const float* __restrict__ be,
                          float* __restrict__ z){
    __shared__ double s2[2];
    __shared__ double s3[2];
    int i = blockIdx.x; int f = threadIdx.x;
    float v = agg[i*H + f] + b[f];
    v = v > 0.f ? v : 0.f;
    int wid = f >> 6;
    double d = (double)v;
    for (int off = 32; off > 0; off >>= 1) d += __shfl_xor(d, off);
    if ((f & 63) == 0) s2[wid] = d;
    __syncthreads();
    double mu = (s2[0] + s2[1]) * (1.0/128.0);
    double dv = (double)v - mu;
    double qq = dv * dv;
    for (int off = 32; off > 0; off >>= 1) qq += __shfl_xor(qq, off);
    if ((f & 63) == 0) s3[wid] = qq;
    __syncthreads();
    double var = (s3[0] + s3[1]) * (1.0/128.0);
    double rs = 1.0 / sqrt(var + 1e-5);
    z[i*H + f] = (float)(dv * rs * (double)g[f] + (double)be[f]);
}
__global__ void k_post64(const float* __restrict__ agg, const float* __restrict__ b,
                         const float* __restrict__ g, const float* __restrict__ be,
                         float* __restrict__ z){
    int i = blockIdx.x; int f = threadIdx.x;
    float v = agg[i*O + f] + b[f];
    v = v > 0.f ? v : 0.f;
    double d = (double)v;
    for (int off = 32; off > 0; off >>= 1) d += __shfl_xor(d, off);
    double mu = d * (1.0/64.0);
    double dv = (double)v - mu;
    double qq = dv * dv;
    for (int off = 32; off > 0; off >>= 1) qq += __shfl_xor(qq, off);
    double var = qq * (1.0/64.0);
    double rs = 1.0 / sqrt(var + 1e-5);
    z[i*O + f] = (float)(dv * rs * (double)g[f] + (double)be[f]);
}

// ---------------- output stores (flag-branched dtype) ----------------
__global__ void k_store(const float* __restrict__ z3, void* __restrict__ outp,
                        const int* __restrict__ flag){
    int i = blockIdx.x*256 + threadIdx.x;
    float v = z3[i];
    if (*flag) ((unsigned short*)outp)[i] = f2bf(v);
    else       ((float*)outp)[i] = v;
}
__global__ void k_edges(const int* __restrict__ topIdx, const float* __restrict__ ewArr,
                        void* __restrict__ outp, const int* __restrict__ flag){
    int e = blockIdx.x*256 + threadIdx.x;
    if (e >= ETOT) return;
    int s, dn; float w;
    if (e < NE){ s = e >> 4; dn = topIdx[e]; w = ewArr[e]; }
    else       { s = e - NE; dn = s;        w = 1.0f; }
    if (*flag){
        unsigned short* o = (unsigned short*)outp;
        o[OUT0 + e]          = f2bf((float)s);
        o[OUT0 + ETOT + e]   = f2bf((float)dn);
        o[OUT0 + 2*ETOT + e] = f2bf(w);
    } else {
        float* o = (float*)outp;
        o[OUT0 + e]          = (float)s;
        o[OUT0 + ETOT + e]   = (float)dn;
        o[OUT0 + 2*ETOT + e] = w;
    }
}

extern "C" void kernel_launch(void* const* d_in, const int* in_sizes, int n_in,
                              void* d_out, int out_size, void* d_ws, size_t ws_size,
                              hipStream_t stream){
    char* ws = (char*)d_ws;
    int*    flag   = (int*)   (ws + 0);
    float*  w1f    = (float*) (ws + 4096);
    float*  b1f    = (float*) (ws + 36864);
    float*  g1f    = (float*) (ws + 37376);
    float*  be1f   = (float*) (ws + 37888);
    float*  w2f    = (float*) (ws + 38400);
    float*  b2f    = (float*) (ws + 71168);
    float*  g2f    = (float*) (ws + 71424);
    float*  be2f   = (float*) (ws + 71680);
    float*  wpf    = (float*) (ws + 71936);
    float*  bpf    = (float*) (ws + 88320);
    float*  xf     = (float*) (ws + 98304);      // 2 MB          -> 2195456
    float*  nrmf   = (float*) (ws + 2195456);    // 32 KB         -> 2228224
    int*    topIdx = (int*)   (ws + 2260992);    // 512 KB        -> 2785280
    float*  ewArr  = (float*) (ws + 2785280);    // 512 KB        -> 3309568
    double* degD   = (double*)(ws + 3309568);    // 64 KB         -> 3375104
    float*  dinv   = (float*) (ws + 3375104);    // 32 KB         -> 3407872
    float*  h1     = (float*) (ws + 3407872);    // 4 MB          -> 7602176
    float*  agg1   = (float*) (ws + 7602176);    // 4 MB          -> 11796480
    float*  z1     = (float*) (ws + 11796480);   // 4 MB          -> 15990784
    float*  h2     = h1;
    float*  agg2   = agg1;
    float*  z2     = z1;
    float*  z3     = h1;
    // topk partials live in the (not-yet-used) agg1 region; dead before k_agg_init
    float*  partV  = (float*) (ws + 7602176);    // 1 MB
    int*    partI  = (int*)   (ws + 8650752);    // 1 MB

    k_probe<<<1, 256, 0, stream>>>((const unsigned short*)d_in[0], flag);
    k_cvt<<<(N*D+255)/256, 256, 0, stream>>>(d_in[0], xf,  N*D, flag);
    k_cvt<<<(D*H+255)/256, 256, 0, stream>>>(d_in[1], w1f, D*H, flag);
    k_cvt<<<1, 256, 0, stream>>>(d_in[2], b1f,  H, flag);
    k_cvt<<<1, 256, 0, stream>>>(d_in[3], g1f,  H, flag);
    k_cvt<<<1, 256, 0, stream>>>(d_in[4], be1f, H, flag);
    k_cvt<<<(H*O+255)/256, 256, 0, stream>>>(d_in[5], w2f, H*O, flag);
    k_cvt<<<1, 256, 0, stream>>>(d_in[6], b2f,  O, flag);
    k_cvt<<<1, 256, 0, stream>>>(d_in[7], g2f,  O, flag);
    k_cvt<<<1, 256, 0, stream>>>(d_in[8], be2f, O, flag);
    k_cvt<<<(O*D+255)/256, 256, 0, stream>>>(d_in[9], wpf, O*D, flag);
    k_cvt<<<1, 256, 0, stream>>>(d_in[10], bpf, D, flag);

    k_prep<<<N/64, 64, 0, stream>>>(xf, nrmf);
    k_topk<<<(N/32)*2, 512, 0, stream>>>(xf, nrmf, partV, partI);
    k_merge<<<N/256, 256, 0, stream>>>(partV, partI, topIdx, ewArr);
    k_deg_init<<<N/256, 256, 0, stream>>>(degD);
    k_deg_scatter<<<NE/256, 256, 0, stream>>>(topIdx, ewArr, degD);
    k_dinv<<<N/256, 256, 0, stream>>>(degD, dinv);

    k_gemm1<<<(N*H)/256, 256, 0, stream>>>(xf, w1f, h1);
    k_agg_init<H><<<(N*H)/256, 256, 0, stream>>>(h1, dinv, agg1);
    k_agg_scat<H><<<NE, H, 0, stream>>>(topIdx, ewArr, dinv, h1, agg1);
    k_post128<<<N, H, 0, stream>>>(agg1, b1f, g1f, be1f, z1);

    k_gemm2<<<(N*O)/256, 256, 0, stream>>>(z1, w2f, h2);
    k_agg_init<O><<<(N*O)/256, 256, 0, stream>>>(h2, dinv, agg2);
    k_agg_scat<O><<<NE, O, 0, stream>>>(topIdx, ewArr, dinv, h2, agg2);
    k_post64<<<N, O, 0, stream>>>(agg2, b2f, g2f, be2f, z2);

    k_proj<<<(N*D)/256, 256, 0, stream>>>(z2, wpf, bpf, z3);
    k_store<<<(N*D)/256, 256, 0, stream>>>(z3, d_out, flag);
    k_edges<<<(ETOT+255)/256, 256, 0, stream>>>(topIdx, ewArr, d_out, flag);
}

// Round 2
// 773.223 us; speedup vs baseline: 6.6303x; 6.6303x over previous
//
#include <hip/hip_runtime.h>
#include <cstdint>
#include <climits>

#define N 8192
#define D 64
#define H 128
#define O 64
#define KNB 16
#define NE (N*KNB)        // 131072
#define ETOT (NE + N)     // 139264
#define OUT0 (N*D)        // 524288

__device__ __forceinline__ float bf2f(unsigned short u){
    union { unsigned int u; float f; } v; v.u = ((unsigned int)u) << 16; return v.f;
}
__device__ __forceinline__ unsigned short f2bf(float f){
    union { float f; unsigned int u; } v; v.f = f;
    unsigned int r = v.u + 0x7FFFu + ((v.u >> 16) & 1u);   // RNE
    return (unsigned short)(r >> 16);
}

// ---------------- dtype probe: 1=bf16 inputs, 0=fp32 inputs ----------------
__global__ void k_probe(const unsigned short* __restrict__ x, int* __restrict__ flag){
    __shared__ int cnt;
    if (threadIdx.x == 0) cnt = 0;
    __syncthreads();
    unsigned short u = x[2*threadIdx.x];
    int e = (u >> 7) & 0xFF;
    int ok = (u == 0) || (e >= 0x60 && e <= 0x85);
    unsigned long long m = __ballot(ok);
    if ((threadIdx.x & 63) == 0) atomicAdd(&cnt, __popcll(m));
    __syncthreads();
    if (threadIdx.x == 0) *flag = (cnt >= 128) ? 1 : 0;
}

// ---------------- generic input convert -> fp32 ----------------
__global__ void k_cvt(const void* __restrict__ src, float* __restrict__ dst,
                      int n, const int* __restrict__ flag){
    int i = blockIdx.x*256 + threadIdx.x;
    if (i >= n) return;
    if (*flag) dst[i] = bf2f(((const unsigned short*)src)[i]);
    else       dst[i] = ((const float*)src)[i];
}

// ---------------- row norms: EXACT numpy fp32 pairwise semantics ----------------
__global__ void k_prep(const float* __restrict__ xf, float* __restrict__ nrmf){
    int i = blockIdx.x*64 + threadIdx.x;
    const float* xr = xf + i*D;
    float r[8];
    #pragma unroll
    for (int q = 0; q < 8; ++q) r[q] = __fmul_rn(xr[q], xr[q]);
    #pragma unroll
    for (int b = 8; b < 64; b += 8)
        #pragma unroll
        for (int q = 0; q < 8; ++q)
            r[q] = __fadd_rn(r[q], __fmul_rn(xr[b+q], xr[b+q]));
    float s = __fadd_rn(__fadd_rn(__fadd_rn(r[0],r[1]), __fadd_rn(r[2],r[3])),
                        __fadd_rn(__fadd_rn(r[4],r[5]), __fadd_rn(r[6],r[7])));
    nrmf[i] = __fsqrt_rn(s);
}

// ---------------- topk: 16 queries/block, j-range split in 2 ----------------
// Grid: 1024 blocks of 256 threads (4 blocks/CU at <=128 VGPR -> 16 waves/CU).
// Block (grp, split): queries i = grp*16+q (q = tid&15), scans j in
// [split*4096, (split+1)*4096). Thread (q, m=tid>>4) runs two interleaved
// fp32 FMA chains (j0 = jbase+m+32s, j1 = j0+16), s in [0,128).
// Sim semantics bitwise-identical to the round-0 passing kernel:
//   sequential fp32 FMA k=0..63, den = fadd(fmul(ni,nj),1e-8), s = fdiv(a,den).
// The divide is deferred behind a provably-conservative prefilter
// (a > thr - |thr|*1e-6, thr = lv[15]*den); an EXACT recheck (s > lv[15])
// gates the insertion, so list evolution is identical.
// Per-query merge of the 16 per-thread sorted lists is a k-way cursor merge:
// heads published to stride-17 LDS (bank-conflict-free), winner shifts its
// register list (statically unrolled). Partial (raw-value) top-16 per split
// goes to global; k_merge fuses the two splits exactly.
// NOTE: plain __launch_bounds__(256) — round-0-proven 120-VGPR allocation.
// (512,4) in the previous attempt drove the allocator to 64 VGPR + full
// spill of the 64-VGPR query row -> 22 GB scratch traffic. Do not re-add.
__global__ __launch_bounds__(256) void k_topk(const float* __restrict__ xf,
                                              const float* __restrict__ nrmf,
                                              float* __restrict__ partVal,
                                              int* __restrict__ partIdx){
    __shared__ float cv[272];   // [q*17 + m] head values
    __shared__ int   ci[272];   // head indices
    __shared__ int   wm[16];    // winning m per query per round

    int tid = threadIdx.x;
    int q = tid & 15, m = tid >> 4;
    int grp = blockIdx.x >> 1;
    int split = blockIdx.x & 1;
    int i = grp*16 + q;
    int jbase = split*4096;

    const float4* xip = (const float4*)(xf + (size_t)i*D);
    float4 xi4[16];
    #pragma unroll
    for (int c = 0; c < 16; ++c) xi4[c] = xip[c];
    float ni = nrmf[i];

    float lv[16]; int li[16];
    #pragma unroll
    for (int r = 0; r < 16; ++r){ lv[r] = -3.0e38f; li[r] = INT_MAX; }

    for (int s = 0; s < 128; ++s){
        int j0 = jbase + m + 32*s;
        int j1 = j0 + 16;
        const float4* A0 = (const float4*)(xf + (size_t)j0*D);
        const float4* A1 = (const float4*)(xf + (size_t)j1*D);
        float a0 = 0.0f, a1 = 0.0f;
        #pragma unroll
        for (int c = 0; c < 16; ++c){
            float4 b0 = A0[c], b1 = A1[c], xa = xi4[c];
            a0 = __fmaf_rn(b0.x, xa.x, a0);
            a0 = __fmaf_rn(b0.y, xa.y, a0);
            a0 = __fmaf_rn(b0.z, xa.z, a0);
            a0 = __fmaf_rn(b0.w, xa.w, a0);
            a1 = __fmaf_rn(b1.x, xa.x, a1);
            a1 = __fmaf_rn(b1.y, xa.y, a1);
            a1 = __fmaf_rn(b1.z, xa.z, a1);
            a1 = __fmaf_rn(b1.w, xa.w, a1);
        }
        float den0 = __fadd_rn(__fmul_rn(ni, nrmf[j0]), 1e-8f);
        float den1 = __fadd_rn(__fmul_rn(ni, nrmf[j1]), 1e-8f);
        // chain 0: conservative prefilter, exact recheck
        float thr0 = lv[15]*den0;
        if (j0 != i && a0 > __fmaf_rn(fabsf(thr0), -1e-6f, thr0)){
            float s0 = __fdiv_rn(a0, den0);
            if (s0 > lv[15]){
                lv[15] = s0; li[15] = j0;
                #pragma unroll
                for (int r = 15; r > 0; --r){
                    if (lv[r] > lv[r-1]){
                        float tv = lv[r]; lv[r] = lv[r-1]; lv[r-1] = tv;
                        int ti = li[r]; li[r] = li[r-1]; li[r-1] = ti;
                    }
                }
            }
        }
        // chain 1 (sees post-chain0 list state, same as before)
        float thr1 = lv[15]*den1;
        if (j1 != i && a1 > __fmaf_rn(fabsf(thr1), -1e-6f, thr1)){
            float s1 = __fdiv_rn(a1, den1);
            if (s1 > lv[15]){
                lv[15] = s1; li[15] = j1;
                #pragma unroll
                for (int r = 15; r > 0; --r){
                    if (lv[r] > lv[r-1]){
                        float tv = lv[r]; lv[r] = lv[r-1]; lv[r-1] = tv;
                        int ti = li[r]; li[r] = li[r-1]; li[r-1] = ti;
                    }
                }
            }
        }
    }

    // publish heads
    cv[q*17 + m] = lv[0];
    ci[q*17 + m] = li[0];
    __syncthreads();

    for (int sel = 0; sel < KNB; ++sel){
        if (tid < 16){
            int q2 = tid;
            float fv = -3.0e38f; int fi = INT_MAX; int fm = 0;
            #pragma unroll
            for (int c = 0; c < 16; ++c){
                float v = cv[q2*17 + c]; int id = ci[q2*17 + c];
                if (v > fv || (v == fv && id < fi)){ fv = v; fi = id; fm = c; }
            }
            int i2 = grp*16 + q2;
            int base = (split*N + i2)*KNB + sel;
            partVal[base] = fv;      // RAW value; threshold applied in k_merge
            partIdx[base] = fi;
            wm[q2] = fm;
        }
        __syncthreads();
        if (sel < KNB-1 && m == wm[q]){
            #pragma unroll
            for (int r = 0; r < 15; ++r){ lv[r] = lv[r+1]; li[r] = li[r+1]; }
            lv[15] = -3.0e38f; li[15] = INT_MAX;
            cv[q*17 + m] = lv[0];
            ci[q*17 + m] = li[0];
        }
        __syncthreads();
    }
}

// ---------------- merge the 2 j-split partial lists per query ----------------
// Split 0 holds j<4096, split 1 holds j>=4096, so the (value desc, idx asc)
// comparator reproduces the exact global ranking.
__global__ void k_merge(const float* __restrict__ pV, const int* __restrict__ pI,
                        int* __restrict__ topIdx, float* __restrict__ ewArr){
    int qq = blockIdx.x*256 + threadIdx.x;
    const float* A  = pV + (size_t)qq*KNB;
    const float* B  = pV + (size_t)(N + qq)*KNB;
    const int*   AI = pI + (size_t)qq*KNB;
    const int*   BI = pI + (size_t)(N + qq)*KNB;
    int ai = 0, bi = 0;
    #pragma unroll
    for (int sel = 0; sel < KNB; ++sel){
        float va = A[ai], vb = B[bi];
        int ia = AI[ai], ib = BI[bi];
        bool tA = (va > vb) || (va == vb && ia < ib);
        float v = tA ? va : vb;
        int  id = tA ? ia : ib;
        ai += tA ? 1 : 0; bi += tA ? 0 : 1;
        topIdx[qq*KNB + sel] = id;
        ewArr [qq*KNB + sel] = (v > 0.5f) ? v : 0.0f;
    }
}

// ---------------- degree / dinv ----------------
__global__ void k_deg_init(double* __restrict__ degD){
    int j = blockIdx.x*blockDim.x + threadIdx.x;
    if (j < N) degD[j] = 2.0;
}
__global__ void k_deg_scatter(const int* __restrict__ topIdx, const float* __restrict__ ewArr,
                              double* __restrict__ degD){
    int e = blockIdx.x*blockDim.x + threadIdx.x;
    if (e < NE){
        float w = ewArr[e];
        if (w > 0.0f) atomicAdd(&degD[topIdx[e]], (double)w);
    }
}
__global__ void k_dinv(const double* __restrict__ degD, float* __restrict__ dinv){
    int j = blockIdx.x*blockDim.x + threadIdx.x;
    if (j < N) dinv[j] = (float)(1.0 / sqrt(degD[j]));
}

// ---------------- dense matmuls ----------------
__global__ void k_gemm1(const float* __restrict__ xf, const float* __restrict__ W1,
                        float* __restrict__ h1){
    int id = blockIdx.x*256 + threadIdx.x;
    int i = id >> 7; int f = id & (H-1);
    const float* xr = xf + i*D;
    float acc = 0.f;
    #pragma unroll
    for (int k = 0; k < D; ++k) acc += xr[k] * W1[k*H + f];
    h1[id] = acc;
}
__global__ void k_gemm2(const float* __restrict__ z1, const float* __restrict__ W2,
                        float* __restrict__ h2){
    int id = blockIdx.x*256 + threadIdx.x;
    int i = id >> 6; int f = id & (O-1);
    const float* zr = z1 + i*H;
    float acc = 0.f;
    #pragma unroll
    for (int k = 0; k < H; ++k) acc += zr[k] * W2[k*O + f];
    h2[id] = acc;
}
__global__ void k_proj(const float* __restrict__ z2, const float* __restrict__ Wp,
                       const float* __restrict__ bp, float* __restrict__ z3){
    int id = blockIdx.x*256 + threadIdx.x;
    int i = id >> 6; int f = id & (D-1);
    const float* zr = z2 + i*O;
    float acc = bp[f];
    #pragma unroll
    for (int k = 0; k < O; ++k) acc += zr[k] * Wp[k*D + f];
    z3[id] = acc;
}

// ---------------- GCN aggregation ----------------
template<int F>
__global__ void k_agg_init(const float* __restrict__ h, const float* __restrict__ dinv,
                           float* __restrict__ agg){
    int id = blockIdx.x*256 + threadIdx.x;
    int j = id / F;
    float dj = dinv[j];
    agg[id] = 2.f * dj * dj * h[id];
}
template<int F>
__global__ void k_agg_scat(const int* __restrict__ topIdx, const float* __restrict__ ewArr,
                           const float* __restrict__ dinv, const float* __restrict__ h,
                           float* __restrict__ agg){
    int e = blockIdx.x; int f = threadIdx.x;
    float w = ewArr[e];
    if (w == 0.f) return;
    int s = e >> 4;
    int dn = topIdx[e];
    float c = dinv[s] * w * dinv[dn];
    atomicAdd(&agg[dn*F + f], c * h[s*F + f]);
}

// ---------------- bias + relu + layernorm ----------------
__global__ void k_post128(const float* __restrict__ agg, const float* __restrict__ b,
                          const float* __restrict__ g, const float* __restrict__ be,
                          float* __restrict__ z){
    __shared__ double s2[2];
    __shared__ double s3[2];
    int i = blockIdx.x; int f = threadIdx.x;
    float v = agg[i*H + f] + b[f];
    v = v > 0.f ? v : 0.f;
    int wid = f >> 6;
    double d = (double)v;
    for (int off = 32; off > 0; off >>= 1) d += __shfl_xor(d, off);
    if ((f & 63) == 0) s2[wid] = d;
    __syncthreads();
    double mu = (s2[0] + s2[1]) * (1.0/128.0);
    double dv = (double)v - mu;
    double qq = dv * dv;
    for (int off = 32; off > 0; off >>= 1) qq += __shfl_xor(qq, off);
    if ((f & 63) == 0) s3[wid] = qq;
    __syncthreads();
    double var = (s3[0] + s3[1]) * (1.0/128.0);
    double rs = 1.0 / sqrt(var + 1e-5);
    z[i*H + f] = (float)(dv * rs * (double)g[f] + (double)be[f]);
}
__global__ void k_post64(const float* __restrict__ agg, const float* __restrict__ b,
                         const float* __restrict__ g, const float* __restrict__ be,
                         float* __restrict__ z){
    int i = blockIdx.x; int f = threadIdx.x;
    float v = agg[i*O + f] + b[f];
    v = v > 0.f ? v : 0.f;
    double d = (double)v;
    for (int off = 32; off > 0; off >>= 1) d += __shfl_xor(d, off);
    double mu = d * (1.0/64.0);
    double dv = (double)v - mu;
    double qq = dv * dv;
    for (int off = 32; off > 0; off >>= 1) qq += __shfl_xor(qq, off);
    double var = qq * (1.0/64.0);
    double rs = 1.0 / sqrt(var + 1e-5);
    z[i*O + f] = (float)(dv * rs * (double)g[f] + (double)be[f]);
}

// ---------------- output stores (flag-branched dtype) ----------------
__global__ void k_store(const float* __restrict__ z3, void* __restrict__ outp,
                        const int* __restrict__ flag){
    int i = blockIdx.x*256 + threadIdx.x;
    float v = z3[i];
    if (*flag) ((unsigned short*)outp)[i] = f2bf(v);
    else       ((float*)outp)[i] = v;
}
__global__ void k_edges(const int* __restrict__ topIdx, const float* __restrict__ ewArr,
                        void* __restrict__ outp, const int* __restrict__ flag){
    int e = blockIdx.x*256 + threadIdx.x;
    if (e >= ETOT) return;
    int s, dn; float w;
    if (e < NE){ s = e >> 4; dn = topIdx[e]; w = ewArr[e]; }
    else       { s = e - NE; dn = s;        w = 1.0f; }
    if (*flag){
        unsigned short* o = (unsigned short*)outp;
        o[OUT0 + e]          = f2bf((float)s);
        o[OUT0 + ETOT + e]   = f2bf((float)dn);
        o[OUT0 + 2*ETOT + e] = f2bf(w);
    } else {
        float* o = (float*)outp;
        o[OUT0 + e]          = (float)s;
        o[OUT0 + ETOT + e]   = (float)dn;
        o[OUT0 + 2*ETOT + e] = w;
    }
}

extern "C" void kernel_launch(void* const* d_in, const int* in_sizes, int n_in,
                              void* d_out, int out_size, void* d_ws, size_t ws_size,
                              hipStream_t stream){
    char* ws = (char*)d_ws;
    int*    flag   = (int*)   (ws + 0);
    float*  w1f    = (float*) (ws + 4096);
    float*  b1f    = (float*) (ws + 36864);
    float*  g1f    = (float*) (ws + 37376);
    float*  be1f   = (float*) (ws + 37888);
    float*  w2f    = (float*) (ws + 38400);
    float*  b2f    = (float*) (ws + 71168);
    float*  g2f    = (float*) (ws + 71424);
    float*  be2f   = (float*) (ws + 71680);
    float*  wpf    = (float*) (ws + 71936);
    float*  bpf    = (float*) (ws + 88320);
    float*  xf     = (float*) (ws + 98304);      // 2 MB          -> 2195456
    float*  nrmf   = (float*) (ws + 2195456);    // 32 KB         -> 2228224
    int*    topIdx = (int*)   (ws + 2260992);    // 512 KB        -> 2785280
    float*  ewArr  = (float*) (ws + 2785280);    // 512 KB        -> 3309568
    double* degD   = (double*)(ws + 3309568);    // 64 KB         -> 3375104
    float*  dinv   = (float*) (ws + 3375104);    // 32 KB         -> 3407872
    float*  h1     = (float*) (ws + 3407872);    // 4 MB          -> 7602176
    float*  agg1   = (float*) (ws + 7602176);    // 4 MB          -> 11796480
    float*  z1     = (float*) (ws + 11796480);   // 4 MB          -> 15990784
    float*  h2     = h1;
    float*  agg2   = agg1;
    float*  z2     = z1;
    float*  z3     = h1;
    // topk partials live in the (not-yet-used) agg1 region; dead before k_agg_init
    float*  partV  = (float*) (ws + 7602176);    // 1 MB
    int*    partI  = (int*)   (ws + 8650752);    // 1 MB

    k_probe<<<1, 256, 0, stream>>>((const unsigned short*)d_in[0], flag);
    k_cvt<<<(N*D+255)/256, 256, 0, stream>>>(d_in[0], xf,  N*D, flag);
    k_cvt<<<(D*H+255)/256, 256, 0, stream>>>(d_in[1], w1f, D*H, flag);
    k_cvt<<<1, 256, 0, stream>>>(d_in[2], b1f,  H, flag);
    k_cvt<<<1, 256, 0, stream>>>(d_in[3], g1f,  H, flag);
    k_cvt<<<1, 256, 0, stream>>>(d_in[4], be1f, H, flag);
    k_cvt<<<(H*O+255)/256, 256, 0, stream>>>(d_in[5], w2f, H*O, flag);
    k_cvt<<<1, 256, 0, stream>>>(d_in[6], b2f,  O, flag);
    k_cvt<<<1, 256, 0, stream>>>(d_in[7], g2f,  O, flag);
    k_cvt<<<1, 256, 0, stream>>>(d_in[8], be2f, O, flag);
    k_cvt<<<(O*D+255)/256, 256, 0, stream>>>(d_in[9], wpf, O*D, flag);
    k_cvt<<<1, 256, 0, stream>>>(d_in[10], bpf, D, flag);

    k_prep<<<N/64, 64, 0, stream>>>(xf, nrmf);
    k_topk<<<(N/16)*2, 256, 0, stream>>>(xf, nrmf, partV, partI);
    k_merge<<<N/256, 256, 0, stream>>>(partV, partI, topIdx, ewArr);
    k_deg_init<<<N/256, 256, 0, stream>>>(degD);
    k_deg_scatter<<<NE/256, 256, 0, stream>>>(topIdx, ewArr, degD);
    k_dinv<<<N/256, 256, 0, stream>>>(degD, dinv);

    k_gemm1<<<(N*H)/256, 256, 0, stream>>>(xf, w1f, h1);
    k_agg_init<H><<<(N*H)/256, 256, 0, stream>>>(h1, dinv, agg1);
    k_agg_scat<H><<<NE, H, 0, stream>>>(topIdx, ewArr, dinv, h1, agg1);
    k_post128<<<N, H, 0, stream>>>(agg1, b1f, g1f, be1f, z1);

    k_gemm2<<<(N*O)/256, 256, 0, stream>>>(z1, w2f, h2);
    k_agg_init<O><<<(N*O)/256, 256, 0, stream>>>(h2, dinv, agg2);
    k_agg_scat<O><<<NE, O, 0, stream>>>(topIdx, ewArr, dinv, h2, agg2);
    k_post64<<<N, O, 0, stream>>>(agg2, b2f, g2f, be2f, z2);

    k_proj<<<(N*D)/256, 256, 0, stream>>>(z2, wpf, bpf, z3);
    k_store<<<(N*D)/256, 256, 0, stream>>>(z3, d_out, flag);
    k_edges<<<(ETOT+255)/256, 256, 0, stream>>>(topIdx, ewArr, d_out, flag);
}

// Round 3
// 736.229 us; speedup vs baseline: 6.9635x; 1.0502x over previous
//
#include <hip/hip_runtime.h>
#include <cstdint>
#include <climits>

#define N 8192
#define D 64
#define H 128
#define O 64
#define KNB 16
#define NE (N*KNB)        // 131072
#define ETOT (NE + N)     // 139264
#define OUT0 (N*D)        // 524288

__device__ __forceinline__ float bf2f(unsigned short u){
    union { unsigned int u; float f; } v; v.u = ((unsigned int)u) << 16; return v.f;
}
__device__ __forceinline__ unsigned short f2bf(float f){
    union { float f; unsigned int u; } v; v.f = f;
    unsigned int r = v.u + 0x7FFFu + ((v.u >> 16) & 1u);   // RNE
    return (unsigned short)(r >> 16);
}

// ---------------- dtype probe: 1=bf16 inputs, 0=fp32 inputs ----------------
__global__ void k_probe(const unsigned short* __restrict__ x, int* __restrict__ flag){
    __shared__ int cnt;
    if (threadIdx.x == 0) cnt = 0;
    __syncthreads();
    unsigned short u = x[2*threadIdx.x];
    int e = (u >> 7) & 0xFF;
    int ok = (u == 0) || (e >= 0x60 && e <= 0x85);
    unsigned long long m = __ballot(ok);
    if ((threadIdx.x & 63) == 0) atomicAdd(&cnt, __popcll(m));
    __syncthreads();
    if (threadIdx.x == 0) *flag = (cnt >= 128) ? 1 : 0;
}

// ---------------- generic input convert -> fp32 ----------------
__global__ void k_cvt(const void* __restrict__ src, float* __restrict__ dst,
                      int n, const int* __restrict__ flag){
    int i = blockIdx.x*256 + threadIdx.x;
    if (i >= n) return;
    if (*flag) dst[i] = bf2f(((const unsigned short*)src)[i]);
    else       dst[i] = ((const float*)src)[i];
}

// ---------------- row norms: EXACT numpy fp32 pairwise semantics ----------------
__global__ void k_prep(const float* __restrict__ xf, float* __restrict__ nrmf){
    int i = blockIdx.x*64 + threadIdx.x;
    const float* xr = xf + i*D;
    float r[8];
    #pragma unroll
    for (int q = 0; q < 8; ++q) r[q] = __fmul_rn(xr[q], xr[q]);
    #pragma unroll
    for (int b = 8; b < 64; b += 8)
        #pragma unroll
        for (int q = 0; q < 8; ++q)
            r[q] = __fadd_rn(r[q], __fmul_rn(xr[b+q], xr[b+q]));
    float s = __fadd_rn(__fadd_rn(__fadd_rn(r[0],r[1]), __fadd_rn(r[2],r[3])),
                        __fadd_rn(__fadd_rn(r[4],r[5]), __fadd_rn(r[6],r[7])));
    nrmf[i] = __fsqrt_rn(s);
}

// ---------------- topk: one query PER LANE, wave-uniform j-loop ----------------
// Round-2 post-mortem: q=tid&15 layout made every float4 load carry 4 distinct
// cache lines -> TA (vector-memory issue) demand was 2x VALU demand ->
// VALUBusy pinned at ~51%. Here each lane owns one query row in 64 VGPRs and
// the j-loop address is wave-uniform (broadcast / scalarizable to s_load):
// ~16 TA cyc vs 128 VALU cyc per j per wave -> VALU-bound.
// Grid: 32 query-groups x nsplit j-splits. Per-thread: jspan sequential j's.
// Sim semantics bitwise-identical to the round-0/2 passing kernels:
//   sequential fp32 FMA k=0..63, den = fadd(fmul(ni,nj),1e-8), s = fdiv(a,den).
// Divide deferred behind the provably-conservative prefilter with EXACT
// recheck (s > lv[15]) -> list evolution identical to computing s for all j.
// NOTE: plain __launch_bounds__(256) — (512,4) previously forced 64-VGPR
// allocation + full spill of the query row (22 GB scratch). Do not re-add.
__global__ __launch_bounds__(256) void k_topk(const float* __restrict__ xf,
                                              const float* __restrict__ nrmf,
                                              float* __restrict__ partVal,
                                              int* __restrict__ partIdx,
                                              int jspan){
    int tid = threadIdx.x;
    int grp = blockIdx.x & 31;        // 32 query groups of 256
    int split = blockIdx.x >> 5;      // j-split index
    int i = grp*256 + tid;
    int jbase = split*jspan;

    const float4* xip = (const float4*)(xf + (size_t)i*D);
    float4 xi4[16];
    #pragma unroll
    for (int c = 0; c < 16; ++c) xi4[c] = xip[c];
    float ni = nrmf[i];

    float lv[16]; int li[16];
    #pragma unroll
    for (int r = 0; r < 16; ++r){ lv[r] = -3.0e38f; li[r] = INT_MAX; }

    for (int jj = 0; jj < jspan; ++jj){
        int j = jbase + jj;                         // wave-uniform
        const float4* A = (const float4*)(xf + (size_t)j*D);
        float nj = nrmf[j];
        float a = 0.0f;
        #pragma unroll
        for (int c = 0; c < 16; ++c){
            float4 b = A[c]; float4 xa = xi4[c];    // b uniform across lanes
            a = __fmaf_rn(b.x, xa.x, a);
            a = __fmaf_rn(b.y, xa.y, a);
            a = __fmaf_rn(b.z, xa.z, a);
            a = __fmaf_rn(b.w, xa.w, a);
        }
        float den = __fadd_rn(__fmul_rn(ni, nj), 1e-8f);
        float thr = lv[15]*den;
        if (j != i && a > __fmaf_rn(fabsf(thr), -1e-6f, thr)){
            float s0 = __fdiv_rn(a, den);
            if (s0 > lv[15]){
                lv[15] = s0; li[15] = j;
                #pragma unroll
                for (int r = 15; r > 0; --r){
                    if (lv[r] > lv[r-1]){
                        float tv = lv[r]; lv[r] = lv[r-1]; lv[r-1] = tv;
                        int ti = li[r]; li[r] = li[r-1]; li[r-1] = ti;
                    }
                }
            }
        }
    }

    // store raw sorted per-split list (always 16 real entries: jspan-1 >= 16)
    float* pv = partVal + ((size_t)split*N + i)*KNB;
    int*   pi = partIdx + ((size_t)split*N + i)*KNB;
    #pragma unroll
    for (int r = 0; r < 16; ++r){ pv[r] = lv[r]; pi[r] = li[r]; }
}

// ---------------- pairwise tournament merge of split lists ----------------
// Merges list (s) with list (s+half) into slot (s), per query. A-list is
// held in registers with a static shift (no runtime register indexing, no
// in-place read/write hazard); B-list is cursor-read from global.
// Comparator (value desc, idx asc) == jax.lax.top_k stable tie-break.
__global__ void k_mtree(float* __restrict__ pV, int* __restrict__ pI, int half){
    int t = blockIdx.x*256 + threadIdx.x;   // t < half*N
    int s = t >> 13;                         // t / N
    int q = t & (N-1);
    float* Av = pV + ((size_t)s*N + q)*KNB;
    int*   Ax = pI + ((size_t)s*N + q)*KNB;
    const float* Bv = pV + ((size_t)(s+half)*N + q)*KNB;
    const int*   Bx = pI + ((size_t)(s+half)*N + q)*KNB;
    float av[16]; int ax[16];
    #pragma unroll
    for (int r = 0; r < 16; ++r){ av[r] = Av[r]; ax[r] = Ax[r]; }
    int bi = 0;
    #pragma unroll
    for (int sel = 0; sel < KNB; ++sel){
        float vb = Bv[bi]; int ib = Bx[bi];
        bool tA = (av[0] > vb) || (av[0] == vb && ax[0] < ib);
        Av[sel] = tA ? av[0] : vb;
        Ax[sel] = tA ? ax[0] : ib;
        if (tA){
            #pragma unroll
            for (int r = 0; r < 15; ++r){ av[r] = av[r+1]; ax[r] = ax[r+1]; }
        } else ++bi;
    }
}
// final merge (split 0 with split 1) -> topIdx/ewArr with 0.5 threshold
__global__ void k_mfinal(const float* __restrict__ pV, const int* __restrict__ pI,
                         int* __restrict__ topIdx, float* __restrict__ ewArr){
    int q = blockIdx.x*256 + threadIdx.x;
    const float* Av = pV + (size_t)q*KNB;
    const int*   Ax = pI + (size_t)q*KNB;
    const float* Bv = pV + ((size_t)N + q)*KNB;
    const int*   Bx = pI + ((size_t)N + q)*KNB;
    float av[16]; int ax[16];
    #pragma unroll
    for (int r = 0; r < 16; ++r){ av[r] = Av[r]; ax[r] = Ax[r]; }
    int bi = 0;
    #pragma unroll
    for (int sel = 0; sel < KNB; ++sel){
        float vb = Bv[bi]; int ib = Bx[bi];
        bool tA = (av[0] > vb) || (av[0] == vb && ax[0] < ib);
        float v = tA ? av[0] : vb;
        int  id = tA ? ax[0] : ib;
        if (tA){
            #pragma unroll
            for (int r = 0; r < 15; ++r){ av[r] = av[r+1]; ax[r] = ax[r+1]; }
        } else ++bi;
        topIdx[q*KNB + sel] = id;
        ewArr [q*KNB + sel] = (v > 0.5f) ? v : 0.0f;
    }
}

// ---------------- degree / dinv ----------------
__global__ void k_deg_init(double* __restrict__ degD){
    int j = blockIdx.x*blockDim.x + threadIdx.x;
    if (j < N) degD[j] = 2.0;
}
__global__ void k_deg_scatter(const int* __restrict__ topIdx, const float* __restrict__ ewArr,
                              double* __restrict__ degD){
    int e = blockIdx.x*blockDim.x + threadIdx.x;
    if (e < NE){
        float w = ewArr[e];
        if (w > 0.0f) atomicAdd(&degD[topIdx[e]], (double)w);
    }
}
__global__ void k_dinv(const double* __restrict__ degD, float* __restrict__ dinv){
    int j = blockIdx.x*blockDim.x + threadIdx.x;
    if (j < N) dinv[j] = (float)(1.0 / sqrt(degD[j]));
}

// ---------------- dense matmuls ----------------
__global__ void k_gemm1(const float* __restrict__ xf, const float* __restrict__ W1,
                        float* __restrict__ h1){
    int id = blockIdx.x*256 + threadIdx.x;
    int i = id >> 7; int f = id & (H-1);
    const float* xr = xf + i*D;
    float acc = 0.f;
    #pragma unroll
    for (int k = 0; k < D; ++k) acc += xr[k] * W1[k*H + f];
    h1[id] = acc;
}
__global__ void k_gemm2(const float* __restrict__ z1, const float* __restrict__ W2,
                        float* __restrict__ h2){
    int id = blockIdx.x*256 + threadIdx.x;
    int i = id >> 6; int f = id & (O-1);
    const float* zr = z1 + i*H;
    float acc = 0.f;
    #pragma unroll
    for (int k = 0; k < H; ++k) acc += zr[k] * W2[k*O + f];
    h2[id] = acc;
}
__global__ void k_proj(const float* __restrict__ z2, const float* __restrict__ Wp,
                       const float* __restrict__ bp, float* __restrict__ z3){
    int id = blockIdx.x*256 + threadIdx.x;
    int i = id >> 6; int f = id & (D-1);
    const float* zr = z2 + i*O;
    float acc = bp[f];
    #pragma unroll
    for (int k = 0; k < O; ++k) acc += zr[k] * Wp[k*D + f];
    z3[id] = acc;
}

// ---------------- GCN aggregation ----------------
template<int F>
__global__ void k_agg_init(const float* __restrict__ h, const float* __restrict__ dinv,
                           float* __restrict__ agg){
    int id = blockIdx.x*256 + threadIdx.x;
    int j = id / F;
    float dj = dinv[j];
    agg[id] = 2.f * dj * dj * h[id];
}
template<int F>
__global__ void k_agg_scat(const int* __restrict__ topIdx, const float* __restrict__ ewArr,
                           const float* __restrict__ dinv, const float* __restrict__ h,
                           float* __restrict__ agg){
    int e = blockIdx.x; int f = threadIdx.x;
    float w = ewArr[e];
    if (w == 0.f) return;
    int s = e >> 4;
    int dn = topIdx[e];
    float c = dinv[s] * w * dinv[dn];
    atomicAdd(&agg[dn*F + f], c * h[s*F + f]);
}

// ---------------- bias + relu + layernorm ----------------
__global__ void k_post128(const float* __restrict__ agg, const float* __restrict__ b,
                          const float* __restrict__ g, const float* __restrict__ be,
                          float* __restrict__ z){
    __shared__ double s2[2];
    __shared__ double s3[2];
    int i = blockIdx.x; int f = threadIdx.x;
    float v = agg[i*H + f] + b[f];
    v = v > 0.f ? v : 0.f;
    int wid = f >> 6;
    double d = (double)v;
    for (int off = 32; off > 0; off >>= 1) d += __shfl_xor(d, off);
    if ((f & 63) == 0) s2[wid] = d;
    __syncthreads();
    double mu = (s2[0] + s2[1]) * (1.0/128.0);
    double dv = (double)v - mu;
    double qq = dv * dv;
    for (int off = 32; off > 0; off >>= 1) qq += __shfl_xor(qq, off);
    if ((f & 63) == 0) s3[wid] = qq;
    __syncthreads();
    double var = (s3[0] + s3[1]) * (1.0/128.0);
    double rs = 1.0 / sqrt(var + 1e-5);
    z[i*H + f] = (float)(dv * rs * (double)g[f] + (double)be[f]);
}
__global__ void k_post64(const float* __restrict__ agg, const float* __restrict__ b,
                         const float* __restrict__ g, const float* __restrict__ be,
                         float* __restrict__ z){
    int i = blockIdx.x; int f = threadIdx.x;
    float v = agg[i*O + f] + b[f];
    v = v > 0.f ? v : 0.f;
    double d = (double)v;
    for (int off = 32; off > 0; off >>= 1) d += __shfl_xor(d, off);
    double mu = d * (1.0/64.0);
    double dv = (double)v - mu;
    double qq = dv * dv;
    for (int off = 32; off > 0; off >>= 1) qq += __shfl_xor(qq, off);
    double var = qq * (1.0/64.0);
    double rs = 1.0 / sqrt(var + 1e-5);
    z[i*O + f] = (float)(dv * rs * (double)g[f] + (double)be[f]);
}

// ---------------- output stores (flag-branched dtype) ----------------
__global__ void k_store(const float* __restrict__ z3, void* __restrict__ outp,
                        const int* __restrict__ flag){
    int i = blockIdx.x*256 + threadIdx.x;
    float v = z3[i];
    if (*flag) ((unsigned short*)outp)[i] = f2bf(v);
    else       ((float*)outp)[i] = v;
}
__global__ void k_edges(const int* __restrict__ topIdx, const float* __restrict__ ewArr,
                        void* __restrict__ outp, const int* __restrict__ flag){
    int e = blockIdx.x*256 + threadIdx.x;
    if (e >= ETOT) return;
    int s, dn; float w;
    if (e < NE){ s = e >> 4; dn = topIdx[e]; w = ewArr[e]; }
    else       { s = e - NE; dn = s;        w = 1.0f; }
    if (*flag){
        unsigned short* o = (unsigned short*)outp;
        o[OUT0 + e]          = f2bf((float)s);
        o[OUT0 + ETOT + e]   = f2bf((float)dn);
        o[OUT0 + 2*ETOT + e] = f2bf(w);
    } else {
        float* o = (float*)outp;
        o[OUT0 + e]          = (float)s;
        o[OUT0 + ETOT + e]   = (float)dn;
        o[OUT0 + 2*ETOT + e] = w;
    }
}

extern "C" void kernel_launch(void* const* d_in, const int* in_sizes, int n_in,
                              void* d_out, int out_size, void* d_ws, size_t ws_size,
                              hipStream_t stream){
    char* ws = (char*)d_ws;
    int*    flag   = (int*)   (ws + 0);
    float*  w1f    = (float*) (ws + 4096);
    float*  b1f    = (float*) (ws + 36864);
    float*  g1f    = (float*) (ws + 37376);
    float*  be1f   = (float*) (ws + 37888);
    float*  w2f    = (float*) (ws + 38400);
    float*  b2f    = (float*) (ws + 71168);
    float*  g2f    = (float*) (ws + 71424);
    float*  be2f   = (float*) (ws + 71680);
    float*  wpf    = (float*) (ws + 71936);
    float*  bpf    = (float*) (ws + 88320);
    float*  xf     = (float*) (ws + 98304);      // 2 MB          -> 2195456
    float*  nrmf   = (float*) (ws + 2195456);    // 32 KB         -> 2228224
    int*    topIdx = (int*)   (ws + 2260992);    // 512 KB        -> 2785280
    float*  ewArr  = (float*) (ws + 2785280);    // 512 KB        -> 3309568
    double* degD   = (double*)(ws + 3309568);    // 64 KB         -> 3375104
    float*  dinv   = (float*) (ws + 3375104);    // 32 KB         -> 3407872
    float*  h1     = (float*) (ws + 3407872);    // 4 MB          -> 7602176
    float*  agg1   = (float*) (ws + 7602176);    // 4 MB          -> 11796480
    float*  z1     = (float*) (ws + 11796480);   // 4 MB          -> 15990784
    float*  h2     = h1;
    float*  agg2   = agg1;
    float*  z2     = z1;
    float*  z3     = h1;

    // topk split partials overlap h1/agg1/z1 (dead until k_gemm1, which runs
    // after the merge tree completes). Shrink split count if ws is small.
    const size_t partOff = 3407872;
    int nsplit = 32;
    while (nsplit > 2 &&
           partOff + (size_t)nsplit*N*KNB*8 > ws_size) nsplit >>= 1;
    float* partV = (float*)(ws + partOff);
    int*   partI = (int*)  (ws + partOff + (size_t)nsplit*N*KNB*4);
    int jspan = N / nsplit;

    k_probe<<<1, 256, 0, stream>>>((const unsigned short*)d_in[0], flag);
    k_cvt<<<(N*D+255)/256, 256, 0, stream>>>(d_in[0], xf,  N*D, flag);
    k_cvt<<<(D*H+255)/256, 256, 0, stream>>>(d_in[1], w1f, D*H, flag);
    k_cvt<<<1, 256, 0, stream>>>(d_in[2], b1f,  H, flag);
    k_cvt<<<1, 256, 0, stream>>>(d_in[3], g1f,  H, flag);
    k_cvt<<<1, 256, 0, stream>>>(d_in[4], be1f, H, flag);
    k_cvt<<<(H*O+255)/256, 256, 0, stream>>>(d_in[5], w2f, H*O, flag);
    k_cvt<<<1, 256, 0, stream>>>(d_in[6], b2f,  O, flag);
    k_cvt<<<1, 256, 0, stream>>>(d_in[7], g2f,  O, flag);
    k_cvt<<<1, 256, 0, stream>>>(d_in[8], be2f, O, flag);
    k_cvt<<<(O*D+255)/256, 256, 0, stream>>>(d_in[9], wpf, O*D, flag);
    k_cvt<<<1, 256, 0, stream>>>(d_in[10], bpf, D, flag);

    k_prep<<<N/64, 64, 0, stream>>>(xf, nrmf);
    k_topk<<<32*nsplit, 256, 0, stream>>>(xf, nrmf, partV, partI, jspan);
    for (int half = nsplit/2; half >= 2; half >>= 1)
        k_mtree<<<half*32, 256, 0, stream>>>(partV, partI, half);
    k_mfinal<<<N/256, 256, 0, stream>>>(partV, partI, topIdx, ewArr);

    k_deg_init<<<N/256, 256, 0, stream>>>(degD);
    k_deg_scatter<<<NE/256, 256, 0, stream>>>(topIdx, ewArr, degD);
    k_dinv<<<N/256, 256, 0, stream>>>(degD, dinv);

    k_gemm1<<<(N*H)/256, 256, 0, stream>>>(xf, w1f, h1);
    k_agg_init<H><<<(N*H)/256, 256, 0, stream>>>(h1, dinv, agg1);
    k_agg_scat<H><<<NE, H, 0, stream>>>(topIdx, ewArr, dinv, h1, agg1);
    k_post128<<<N, H, 0, stream>>>(agg1, b1f, g1f, be1f, z1);

    k_gemm2<<<(N*O)/256, 256, 0, stream>>>(z1, w2f, h2);
    k_agg_init<O><<<(N*O)/256, 256, 0, stream>>>(h2, dinv, agg2);
    k_agg_scat<O><<<NE, O, 0, stream>>>(topIdx, ewArr, dinv, h2, agg2);
    k_post64<<<N, O, 0, stream>>>(agg2, b2f, g2f, be2f, z2);

    k_proj<<<(N*D)/256, 256, 0, stream>>>(z2, wpf, bpf, z3);
    k_store<<<(N*D)/256, 256, 0, stream>>>(z3, d_out, flag);
    k_edges<<<(ETOT+255)/256, 256, 0, stream>>>(topIdx, ewArr, d_out, flag);
}

// Round 4
// 708.722 us; speedup vs baseline: 7.2338x; 1.0388x over previous
//
#include <hip/hip_runtime.h>
#include <cstdint>
#include <climits>

#define N 8192
#define D 64
#define H 128
#define O 64
#define KNB 16
#define NE (N*KNB)        // 131072
#define ETOT (NE + N)     // 139264
#define OUT0 (N*D)        // 524288
#define NSPL 32           // j-splits for scan kernels
#define JSPAN 256         // j's per split (N/NSPL)
#define CAP 96            // candidate buffer per query

__device__ __forceinline__ float bf2f(unsigned short u){
    union { unsigned int u; float f; } v; v.u = ((unsigned int)u) << 16; return v.f;
}
__device__ __forceinline__ unsigned short f2bf(float f){
    union { float f; unsigned int u; } v; v.f = f;
    unsigned int r = v.u + 0x7FFFu + ((v.u >> 16) & 1u);   // RNE
    return (unsigned short)(r >> 16);
}

// ---------------- dtype probe: 1=bf16 inputs, 0=fp32 inputs ----------------
__global__ void k_probe(const unsigned short* __restrict__ x, int* __restrict__ flag){
    __shared__ int cnt;
    if (threadIdx.x == 0) cnt = 0;
    __syncthreads();
    unsigned short u = x[2*threadIdx.x];
    int e = (u >> 7) & 0xFF;
    int ok = (u == 0) || (e >= 0x60 && e <= 0x85);
    unsigned long long m = __ballot(ok);
    if ((threadIdx.x & 63) == 0) atomicAdd(&cnt, __popcll(m));
    __syncthreads();
    if (threadIdx.x == 0) *flag = (cnt >= 128) ? 1 : 0;
}

// ---------------- generic input convert -> fp32 ----------------
__global__ void k_cvt(const void* __restrict__ src, float* __restrict__ dst,
                      int n, const int* __restrict__ flag){
    int i = blockIdx.x*256 + threadIdx.x;
    if (i >= n) return;
    if (*flag) dst[i] = bf2f(((const unsigned short*)src)[i]);
    else       dst[i] = ((const float*)src)[i];
}

// ---------------- row norms: EXACT numpy fp32 pairwise semantics ----------------
__global__ void k_prep(const float* __restrict__ xf, float* __restrict__ nrmf){
    int i = blockIdx.x*64 + threadIdx.x;
    const float* xr = xf + i*D;
    float r[8];
    #pragma unroll
    for (int q = 0; q < 8; ++q) r[q] = __fmul_rn(xr[q], xr[q]);
    #pragma unroll
    for (int b = 8; b < 64; b += 8)
        #pragma unroll
        for (int q = 0; q < 8; ++q)
            r[q] = __fadd_rn(r[q], __fmul_rn(xr[b+q], xr[b+q]));
    float s = __fadd_rn(__fadd_rn(__fadd_rn(r[0],r[1]), __fadd_rn(r[2],r[3])),
                        __fadd_rn(__fadd_rn(r[4],r[5]), __fadd_rn(r[6],r[7])));
    nrmf[i] = __fsqrt_rn(s);
}

// =====================================================================
// Two-pass exact top-k.
// Round-3 post-mortem: per-j 16-deep insertion executes nearly every
// iteration (any-of-64-lanes trigger ~100% at T=256) -> ~5x VALU bloat.
// Fix: selection is order-independent, so (A) cheap scan keeping only
// per-chunk top-2 VALUES, (B) v_i = 16th largest of the 64-value union
// (a subset of row i's sims -> provably <= true 16th largest), (C) rescan
// with fixed threshold v_i appending exact (s,j) candidates (superset of
// the true top-16), (D) exact (value desc, idx asc) selection among
// candidates. All sim values use the verified sequential fp32 FMA chain:
//   a = fma-chain k=0..63; den = fadd(fmul(ni,nj),1e-8); s = fdiv(a,den).
// NOTE: plain __launch_bounds__(256) — (512,4) once forced 64-VGPR alloc
// + full spill of the query row (22 GB scratch). Do not re-add.
// =====================================================================

// ---- pass A: per-lane query, wave-uniform j, keep chunk top-2 values ----
__global__ __launch_bounds__(256) void k_scan2(const float* __restrict__ xf,
                                               const float* __restrict__ nrmf,
                                               float* __restrict__ chunk2){
    int tid = threadIdx.x;
    int grp = blockIdx.x & 31;        // 32 query groups of 256
    int split = blockIdx.x >> 5;      // 32 j-splits
    int i = grp*256 + tid;
    int jbase = split*JSPAN;

    const float4* xip = (const float4*)(xf + (size_t)i*D);
    float4 xi4[16];
    #pragma unroll
    for (int c = 0; c < 16; ++c) xi4[c] = xip[c];
    float ni = nrmf[i];

    float v0 = -3.0e38f, v1 = -3.0e38f;   // chunk top-2 values

    for (int jj = 0; jj < JSPAN; ++jj){
        int j = jbase + jj;                         // wave-uniform
        const float4* A = (const float4*)(xf + (size_t)j*D);
        float nj = nrmf[j];
        float a = 0.0f;
        #pragma unroll
        for (int c = 0; c < 16; ++c){
            float4 b = A[c]; float4 xa = xi4[c];    // b uniform across lanes
            a = __fmaf_rn(b.x, xa.x, a);
            a = __fmaf_rn(b.y, xa.y, a);
            a = __fmaf_rn(b.z, xa.z, a);
            a = __fmaf_rn(b.w, xa.w, a);
        }
        float den = __fadd_rn(__fmul_rn(ni, nj), 1e-8f);
        float thr = v1*den;
        // conservative prefilter (margin >> fdiv rounding), exact recheck
        if (j != i && a > __fmaf_rn(fabsf(thr), -1e-6f, thr)){
            float s0 = __fdiv_rn(a, den);
            if (s0 > v1){
                if (s0 > v0){ v1 = v0; v0 = s0; } else v1 = s0;
            }
        }
    }
    chunk2[(size_t)i*64 + split*2    ] = v0;
    chunk2[(size_t)i*64 + split*2 + 1] = v1;
}

// ---- v_i = 16th largest of the 64 chunk-top-2 values (subset bound) ----
__global__ void k_vsel(const float* __restrict__ chunk2, float* __restrict__ vthr){
    int i = blockIdx.x*256 + threadIdx.x;
    const float* c = chunk2 + (size_t)i*64;
    float lv[16];
    #pragma unroll
    for (int r = 0; r < 16; ++r) lv[r] = -3.0e38f;
    for (int k = 0; k < 64; ++k){
        float s = c[k];
        if (s > lv[15]){
            lv[15] = s;
            #pragma unroll
            for (int r = 15; r > 0; --r){
                if (lv[r] > lv[r-1]){ float tv = lv[r]; lv[r] = lv[r-1]; lv[r-1] = tv; }
            }
        }
    }
    vthr[i] = lv[15];
}

__global__ void k_zero(int* __restrict__ cnt){
    int i = blockIdx.x*256 + threadIdx.x;
    if (i < N) cnt[i] = 0;
}

// ---- pass B: rescan with fixed threshold, append exact candidates ----
__global__ __launch_bounds__(256) void k_filter(const float* __restrict__ xf,
                                                const float* __restrict__ nrmf,
                                                const float* __restrict__ vthr,
                                                int* __restrict__ cnt,
                                                float* __restrict__ candV,
                                                int* __restrict__ candI){
    int tid = threadIdx.x;
    int grp = blockIdx.x & 31;
    int split = blockIdx.x >> 5;
    int i = grp*256 + tid;
    int jbase = split*JSPAN;

    const float4* xip = (const float4*)(xf + (size_t)i*D);
    float4 xi4[16];
    #pragma unroll
    for (int c = 0; c < 16; ++c) xi4[c] = xip[c];
    float ni = nrmf[i];
    float v = vthr[i];

    for (int jj = 0; jj < JSPAN; ++jj){
        int j = jbase + jj;
        const float4* A = (const float4*)(xf + (size_t)j*D);
        float nj = nrmf[j];
        float a = 0.0f;
        #pragma unroll
        for (int c = 0; c < 16; ++c){
            float4 b = A[c]; float4 xa = xi4[c];
            a = __fmaf_rn(b.x, xa.x, a);
            a = __fmaf_rn(b.y, xa.y, a);
            a = __fmaf_rn(b.z, xa.z, a);
            a = __fmaf_rn(b.w, xa.w, a);
        }
        float den = __fadd_rn(__fmul_rn(ni, nj), 1e-8f);
        float t = v*den;
        // conservative: keep every j with s >= v (den > 0 always)
        if (j != i && a >= __fmaf_rn(fabsf(t), -1e-6f, t)){
            float s0 = __fdiv_rn(a, den);
            if (s0 >= v){
                int slot = atomicAdd(&cnt[i], 1);
                if (slot < CAP){
                    candV[(size_t)i*CAP + slot] = s0;
                    candI[(size_t)i*CAP + slot] = j;
                }
            }
        }
    }
}

// ---- exact top-16 among candidates; serial exact fallback on overflow ----
__global__ __launch_bounds__(64) void k_select(const float* __restrict__ xf,
                                               const float* __restrict__ nrmf,
                                               const int* __restrict__ cnt,
                                               const float* __restrict__ candV,
                                               const int* __restrict__ candI,
                                               int* __restrict__ topIdx,
                                               float* __restrict__ ewArr){
    __shared__ float sv[64*97];   // stride 97: bank-conflict-free per-lane rows
    __shared__ int   si[64*97];
    int t = threadIdx.x;
    int i = blockIdx.x*64 + t;
    int c = cnt[i];
    bool ovf = (c > CAP);
    int cc = ovf ? 0 : c;
    for (int k = 0; k < CAP; ++k){
        bool in = (k < cc);
        sv[t*97 + k] = in ? candV[(size_t)i*CAP + k] : -3.0e38f;
        si[t*97 + k] = in ? candI[(size_t)i*CAP + k] : INT_MAX;
    }
    if (!ovf){
        // guaranteed cc >= 16 (all j with s >= v stored; >=16 such exist)
        #pragma unroll 1
        for (int sel = 0; sel < KNB; ++sel){
            float bv = -3.0e38f; int bi = INT_MAX; int bk = 0;
            for (int k = 0; k < CAP; ++k){
                float vv = sv[t*97 + k]; int id = si[t*97 + k];
                if (vv > bv || (vv == bv && id < bi)){ bv = vv; bi = id; bk = k; }
            }
            sv[t*97 + bk] = -3.0e38f;
            si[t*97 + bk] = INT_MAX;
            topIdx[i*KNB + sel] = bi;
            ewArr [i*KNB + sel] = (bv > 0.5f) ? bv : 0.0f;
        }
    } else {
        // exact serial full scan (expected never on this data; correctness net)
        const float4* xip = (const float4*)(xf + (size_t)i*D);
        float4 xi4[16];
        #pragma unroll
        for (int cc2 = 0; cc2 < 16; ++cc2) xi4[cc2] = xip[cc2];
        float ni = nrmf[i];
        float lv[16]; int li[16];
        #pragma unroll
        for (int r = 0; r < 16; ++r){ lv[r] = -3.0e38f; li[r] = INT_MAX; }
        for (int j = 0; j < N; ++j){
            if (j == i) continue;
            const float4* A = (const float4*)(xf + (size_t)j*D);
            float a = 0.0f;
            #pragma unroll
            for (int cc2 = 0; cc2 < 16; ++cc2){
                float4 b = A[cc2]; float4 xa = xi4[cc2];
                a = __fmaf_rn(b.x, xa.x, a);
                a = __fmaf_rn(b.y, xa.y, a);
                a = __fmaf_rn(b.z, xa.z, a);
                a = __fmaf_rn(b.w, xa.w, a);
            }
            float den = __fadd_rn(__fmul_rn(ni, nrmf[j]), 1e-8f);
            float s0 = __fdiv_rn(a, den);
            if (s0 > lv[15]){   // strict >: ascending j scan == idx-asc ties
                lv[15] = s0; li[15] = j;
                #pragma unroll
                for (int r = 15; r > 0; --r){
                    if (lv[r] > lv[r-1]){
                        float tv = lv[r]; lv[r] = lv[r-1]; lv[r-1] = tv;
                        int ti = li[r]; li[r] = li[r-1]; li[r-1] = ti;
                    }
                }
            }
        }
        #pragma unroll
        for (int sel = 0; sel < KNB; ++sel){
            topIdx[i*KNB + sel] = li[sel];
            ewArr [i*KNB + sel] = (lv[sel] > 0.5f) ? lv[sel] : 0.0f;
        }
    }
}

// ---------------- degree / dinv ----------------
__global__ void k_deg_init(double* __restrict__ degD){
    int j = blockIdx.x*blockDim.x + threadIdx.x;
    if (j < N) degD[j] = 2.0;
}
__global__ void k_deg_scatter(const int* __restrict__ topIdx, const float* __restrict__ ewArr,
                              double* __restrict__ degD){
    int e = blockIdx.x*blockDim.x + threadIdx.x;
    if (e < NE){
        float w = ewArr[e];
        if (w > 0.0f) atomicAdd(&degD[topIdx[e]], (double)w);
    }
}
__global__ void k_dinv(const double* __restrict__ degD, float* __restrict__ dinv){
    int j = blockIdx.x*blockDim.x + threadIdx.x;
    if (j < N) dinv[j] = (float)(1.0 / sqrt(degD[j]));
}

// ---------------- dense matmuls ----------------
__global__ void k_gemm1(const float* __restrict__ xf, const float* __restrict__ W1,
                        float* __restrict__ h1){
    int id = blockIdx.x*256 + threadIdx.x;
    int i = id >> 7; int f = id & (H-1);
    const float* xr = xf + i*D;
    float acc = 0.f;
    #pragma unroll
    for (int k = 0; k < D; ++k) acc += xr[k] * W1[k*H + f];
    h1[id] = acc;
}
__global__ void k_gemm2(const float* __restrict__ z1, const float* __restrict__ W2,
                        float* __restrict__ h2){
    int id = blockIdx.x*256 + threadIdx.x;
    int i = id >> 6; int f = id & (O-1);
    const float* zr = z1 + i*H;
    float acc = 0.f;
    #pragma unroll
    for (int k = 0; k < H; ++k) acc += zr[k] * W2[k*O + f];
    h2[id] = acc;
}
__global__ void k_proj(const float* __restrict__ z2, const float* __restrict__ Wp,
                       const float* __restrict__ bp, float* __restrict__ z3){
    int id = blockIdx.x*256 + threadIdx.x;
    int i = id >> 6; int f = id & (D-1);
    const float* zr = z2 + i*O;
    float acc = bp[f];
    #pragma unroll
    for (int k = 0; k < O; ++k) acc += zr[k] * Wp[k*D + f];
    z3[id] = acc;
}

// ---------------- GCN aggregation ----------------
template<int F>
__global__ void k_agg_init(const float* __restrict__ h, const float* __restrict__ dinv,
                           float* __restrict__ agg){
    int id = blockIdx.x*256 + threadIdx.x;
    int j = id / F;
    float dj = dinv[j];
    agg[id] = 2.f * dj * dj * h[id];
}
template<int F>
__global__ void k_agg_scat(const int* __restrict__ topIdx, const float* __restrict__ ewArr,
                           const float* __restrict__ dinv, const float* __restrict__ h,
                           float* __restrict__ agg){
    int e = blockIdx.x; int f = threadIdx.x;
    float w = ewArr[e];
    if (w == 0.f) return;
    int s = e >> 4;
    int dn = topIdx[e];
    float c = dinv[s] * w * dinv[dn];
    atomicAdd(&agg[dn*F + f], c * h[s*F + f]);
}

// ---------------- bias + relu + layernorm ----------------
__global__ void k_post128(const float* __restrict__ agg, const float* __restrict__ b,
                          const float* __restrict__ g, const float* __restrict__ be,
                          float* __restrict__ z){
    __shared__ double s2[2];
    __shared__ double s3[2];
    int i = blockIdx.x; int f = threadIdx.x;
    float v = agg[i*H + f] + b[f];
    v = v > 0.f ? v : 0.f;
    int wid = f >> 6;
    double d = (double)v;
    for (int off = 32; off > 0; off >>= 1) d += __shfl_xor(d, off);
    if ((f & 63) == 0) s2[wid] = d;
    __syncthreads();
    double mu = (s2[0] + s2[1]) * (1.0/128.0);
    double dv = (double)v - mu;
    double qq = dv * dv;
    for (int off = 32; off > 0; off >>= 1) qq += __shfl_xor(qq, off);
    if ((f & 63) == 0) s3[wid] = qq;
    __syncthreads();
    double var = (s3[0] + s3[1]) * (1.0/128.0);
    double rs = 1.0 / sqrt(var + 1e-5);
    z[i*H + f] = (float)(dv * rs * (double)g[f] + (double)be[f]);
}
__global__ void k_post64(const float* __restrict__ agg, const float* __restrict__ b,
                         const float* __restrict__ g, const float* __restrict__ be,
                         float* __restrict__ z){
    int i = blockIdx.x; int f = threadIdx.x;
    float v = agg[i*O + f] + b[f];
    v = v > 0.f ? v : 0.f;
    double d = (double)v;
    for (int off = 32; off > 0; off >>= 1) d += __shfl_xor(d, off);
    double mu = d * (1.0/64.0);
    double dv = (double)v - mu;
    double qq = dv * dv;
    for (int off = 32; off > 0; off >>= 1) qq += __shfl_xor(qq, off);
    double var = qq * (1.0/64.0);
    double rs = 1.0 / sqrt(var + 1e-5);
    z[i*O + f] = (float)(dv * rs * (double)g[f] + (double)be[f]);
}

// ---------------- output stores (flag-branched dtype) ----------------
__global__ void k_store(const float* __restrict__ z3, void* __restrict__ outp,
                        const int* __restrict__ flag){
    int i = blockIdx.x*256 + threadIdx.x;
    float v = z3[i];
    if (*flag) ((unsigned short*)outp)[i] = f2bf(v);
    else       ((float*)outp)[i] = v;
}
__global__ void k_edges(const int* __restrict__ topIdx, const float* __restrict__ ewArr,
                        void* __restrict__ outp, const int* __restrict__ flag){
    int e = blockIdx.x*256 + threadIdx.x;
    if (e >= ETOT) return;
    int s, dn; float w;
    if (e < NE){ s = e >> 4; dn = topIdx[e]; w = ewArr[e]; }
    else       { s = e - NE; dn = s;        w = 1.0f; }
    if (*flag){
        unsigned short* o = (unsigned short*)outp;
        o[OUT0 + e]          = f2bf((float)s);
        o[OUT0 + ETOT + e]   = f2bf((float)dn);
        o[OUT0 + 2*ETOT + e] = f2bf(w);
    } else {
        float* o = (float*)outp;
        o[OUT0 + e]          = (float)s;
        o[OUT0 + ETOT + e]   = (float)dn;
        o[OUT0 + 2*ETOT + e] = w;
    }
}

extern "C" void kernel_launch(void* const* d_in, const int* in_sizes, int n_in,
                              void* d_out, int out_size, void* d_ws, size_t ws_size,
                              hipStream_t stream){
    char* ws = (char*)d_ws;
    int*    flag   = (int*)   (ws + 0);
    float*  w1f    = (float*) (ws + 4096);
    float*  b1f    = (float*) (ws + 36864);
    float*  g1f    = (float*) (ws + 37376);
    float*  be1f   = (float*) (ws + 37888);
    float*  w2f    = (float*) (ws + 38400);
    float*  b2f    = (float*) (ws + 71168);
    float*  g2f    = (float*) (ws + 71424);
    float*  be2f   = (float*) (ws + 71680);
    float*  wpf    = (float*) (ws + 71936);
    float*  bpf    = (float*) (ws + 88320);
    float*  xf     = (float*) (ws + 98304);      // 2 MB          -> 2195456
    float*  nrmf   = (float*) (ws + 2195456);    // 32 KB         -> 2228224
    int*    topIdx = (int*)   (ws + 2260992);    // 512 KB        -> 2785280
    float*  ewArr  = (float*) (ws + 2785280);    // 512 KB        -> 3309568
    double* degD   = (double*)(ws + 3309568);    // 64 KB         -> 3375104
    float*  dinv   = (float*) (ws + 3375104);    // 32 KB         -> 3407872
    float*  h1     = (float*) (ws + 3407872);    // 4 MB          -> 7602176
    float*  agg1   = (float*) (ws + 7602176);    // 4 MB          -> 11796480
    float*  z1     = (float*) (ws + 11796480);   // 4 MB          -> 15990784
    float*  h2     = h1;
    float*  agg2   = agg1;
    float*  z2     = z1;
    float*  z3     = h1;

    // topk scratch overlaps h1/agg1/z1-head (all dead until k_gemm1, which
    // launches after k_select completes). Total ~11.3 MB < round-3's 37 MB.
    float* chunk2 = (float*)(ws + 3407872);                  // 8192*64*4 = 2 MB
    float* vthr   = (float*)(ws + 3407872 + 2097152);        // 32 KB
    int*   cntb   = (int*)  (ws + 3407872 + 2097152 + 32768);// 32 KB
    float* candV  = (float*)(ws + 3407872 + 2097152 + 65536);            // 3 MB
    int*   candI  = (int*)  (ws + 3407872 + 2097152 + 65536 + 3145728);  // 3 MB

    k_probe<<<1, 256, 0, stream>>>((const unsigned short*)d_in[0], flag);
    k_cvt<<<(N*D+255)/256, 256, 0, stream>>>(d_in[0], xf,  N*D, flag);
    k_cvt<<<(D*H+255)/256, 256, 0, stream>>>(d_in[1], w1f, D*H, flag);
    k_cvt<<<1, 256, 0, stream>>>(d_in[2], b1f,  H, flag);
    k_cvt<<<1, 256, 0, stream>>>(d_in[3], g1f,  H, flag);
    k_cvt<<<1, 256, 0, stream>>>(d_in[4], be1f, H, flag);
    k_cvt<<<(H*O+255)/256, 256, 0, stream>>>(d_in[5], w2f, H*O, flag);
    k_cvt<<<1, 256, 0, stream>>>(d_in[6], b2f,  O, flag);
    k_cvt<<<1, 256, 0, stream>>>(d_in[7], g2f,  O, flag);
    k_cvt<<<1, 256, 0, stream>>>(d_in[8], be2f, O, flag);
    k_cvt<<<(O*D+255)/256, 256, 0, stream>>>(d_in[9], wpf, O*D, flag);
    k_cvt<<<1, 256, 0, stream>>>(d_in[10], bpf, D, flag);

    k_prep<<<N/64, 64, 0, stream>>>(xf, nrmf);
    k_scan2 <<<32*NSPL, 256, 0, stream>>>(xf, nrmf, chunk2);
    k_vsel  <<<N/256, 256, 0, stream>>>(chunk2, vthr);
    k_zero  <<<N/256, 256, 0, stream>>>(cntb);
    k_filter<<<32*NSPL, 256, 0, stream>>>(xf, nrmf, vthr, cntb, candV, candI);
    k_select<<<N/64, 64, 0, stream>>>(xf, nrmf, cntb, candV, candI, topIdx, ewArr);

    k_deg_init<<<N/256, 256, 0, stream>>>(degD);
    k_deg_scatter<<<NE/256, 256, 0, stream>>>(topIdx, ewArr, degD);
    k_dinv<<<N/256, 256, 0, stream>>>(degD, dinv);

    k_gemm1<<<(N*H)/256, 256, 0, stream>>>(xf, w1f, h1);
    k_agg_init<H><<<(N*H)/256, 256, 0, stream>>>(h1, dinv, agg1);
    k_agg_scat<H><<<NE, H, 0, stream>>>(topIdx, ewArr, dinv, h1, agg1);
    k_post128<<<N, H, 0, stream>>>(agg1, b1f, g1f, be1f, z1);

    k_gemm2<<<(N*O)/256, 256, 0, stream>>>(z1, w2f, h2);
    k_agg_init<O><<<(N*O)/256, 256, 0, stream>>>(h2, dinv, agg2);
    k_agg_scat<O><<<NE, O, 0, stream>>>(topIdx, ewArr, dinv, h2, agg2);
    k_post64<<<N, O, 0, stream>>>(agg2, b2f, g2f, be2f, z2);

    k_proj<<<(N*D)/256, 256, 0, stream>>>(z2, wpf, bpf, z3);
    k_store<<<(N*D)/256, 256, 0, stream>>>(z3, d_out, flag);
    k_edges<<<(ETOT+255)/256, 256, 0, stream>>>(topIdx, ewArr, d_out, flag);
}